// Round 9
// baseline (54.041 us; speedup 1.0000x reference)
//
#include <hip/hip_runtime.h>

#pragma clang fp contract(off)

#define HH 96
#define WW 96
#define KK 16
#define MM 2
#define NF 512            // M * Fm
#define NPIX (HH*WW)      // 9216
#define TDIM 12           // tiles per side
#define TSZ 8             // pixels per tile side
#define NTILE (TDIM*TDIM) // 144
#define MAXC 8            // max list chunks (NF/64)

#define SIGMA_F 1e-4f
#define GAMMA_F 1e-4f
#define BLUR_F  9.210240366975851e-4f   // log(1/1e-4 - 1) * 1e-4 -> f32
#define EPS_F   1e-10f
#define ZFAR_F  100.0f
#define ZNEAR_F 1.0f
#define RM      0.0304f                 // > sqrt(BLUR_F) = 0.0303484

#define SENT 0xFFFFFFFFFFFFFFFFull

__device__ __forceinline__ float frcp(float x) { return __builtin_amdgcn_rcpf(x); }

__device__ __forceinline__ float edge_d2(float px, float py,
                                         float ax, float ay,
                                         float bx, float by) {
    float abx = bx - ax, aby = by - ay;
    float apx = px - ax, apy = py - ay;
    float t = (apx*abx + apy*aby) * frcp(abx*abx + aby*aby + 1e-12f);
    t = fminf(fmaxf(t, 0.0f), 1.0f);
    float dx = apx - t*abx, dy = apy - t*aby;
    return dx*dx + dy*dy;
}

struct Rast { float b0, b1, b2, zpix, dists; };

// geo-packed layout: g0=(x0,y0,x1,y1) g1=(x2,y2,z0,z1) g2=(z2,-,-,-)
__device__ __forceinline__ Rast rasterize_g(float px, float py,
                                            float4 g0, float4 g1, float4 g2) {
    Rast r;
    float v0x=g0.x, v0y=g0.y, v1x=g0.z, v1y=g0.w, v2x=g1.x, v2y=g1.y;
    float z0=g1.z, z1=g1.w, z2=g2.x;
    float e1x=v1x-v0x, e1y=v1y-v0y, e2x=v2x-v0x, e2y=v2y-v0y;
    float dx=px-v0x, dy=py-v0y;
    float rden = frcp(e1x*e2y - e1y*e2x + 1e-12f);
    r.b1 = (dx*e2y - dy*e2x) * rden;
    r.b2 = (e1x*dy - e1y*dx) * rden;
    r.b0 = 1.0f - r.b1 - r.b2;
    r.zpix = r.b0*z0 + r.b1*z1 + r.b2*z2;
    bool inside = (r.b0 >= 0.0f) && (r.b1 >= 0.0f) && (r.b2 >= 0.0f);
    float d2 = edge_d2(px, py, v0x, v0y, v1x, v1y);
    d2 = fminf(d2, edge_d2(px, py, v1x, v1y, v2x, v2y));
    d2 = fminf(d2, edge_d2(px, py, v2x, v2y, v0x, v0y));
    r.dists = inside ? -d2 : d2;
    return r;
}

__device__ __forceinline__ unsigned long long packzf(float z, int f) {
    return (((unsigned long long)__float_as_uint(z)) << 32) | (unsigned int)f;
}

__device__ __forceinline__ unsigned long long shflx64(unsigned long long v, int m) {
    int lo = __shfl_xor((int)(unsigned)(v & 0xffffffffull), m, 64);
    int hi = __shfl_xor((int)(unsigned)(v >> 32), m, 64);
    return ((unsigned long long)(unsigned)hi << 32) | (unsigned)lo;
}

__device__ __forceinline__ void agg_face(float px, float py,
                                         const float4* __restrict__ geop,
                                         const float4* __restrict__ colp,
                                         int bf, float z, float zmaxv,
                                         float& nr, float& ng, float& nb,
                                         float& dn, float& ap) {
    float4 g0 = geop[bf*3+0], g1 = geop[bf*3+1], g2 = geop[bf*3+2];
    float4 c0 = colp[bf*3+0], c1 = colp[bf*3+1], c2 = colp[bf*3+2];
    Rast r = rasterize_g(px, py, g0, g1, g2);
    float prob = frcp(1.0f + __expf(r.dists / SIGMA_F));
    float zinv = (ZFAR_F - z) / (ZFAR_F - ZNEAR_F);
    float w = prob * __expf((zinv - zmaxv) / GAMMA_F);
    nr += w * (r.b0*c0.x + r.b1*c1.x + r.b2*c2.x);
    ng += w * (r.b0*c0.y + r.b1*c1.y + r.b2*c2.y);
    nb += w * (r.b0*c0.z + r.b1*c1.z + r.b2*c2.z);
    dn += w;
    ap *= (1.0f - prob);
}

// ============ kernel 1: stage per-(b,face) bbox/geo/col/key records ============
__global__ void stage_kernel(
    const float* __restrict__ mpos, const float* __restrict__ mrot,
    const float* __restrict__ mscale, const float* __restrict__ cpos,
    const float* __restrict__ crot, const float* __restrict__ verts,
    const int* __restrict__ faces, const float* __restrict__ vcol,
    float4* __restrict__ ws, float* __restrict__ kraw)
{
    const int b = blockIdx.x / MM, m = blockIdx.x % MM, t = threadIdx.x;
    const int B = gridDim.x / MM;
    const int BF = B * NF;
    __shared__ float sx[256], sy[256], sz[256];

    float cr[9];
    #pragma unroll
    for (int i = 0; i < 9; ++i) cr[i] = crot[b*9 + i];
    const float cpx = cpos[b*3+0], cpy = cpos[b*3+1], cpz = cpos[b*3+2];

    {
        int sb = (b*MM + m)*3, rb = (b*MM + m)*9;
        int vid = m*256 + t;
        float v0 = verts[vid*3+0] * mscale[sb+0];
        float v1 = verts[vid*3+1] * mscale[sb+1];
        float v2 = verts[vid*3+2] * mscale[sb+2];
        float wx = mrot[rb+0]*v0 + mrot[rb+1]*v1 + mrot[rb+2]*v2 + mpos[sb+0];
        float wy = mrot[rb+3]*v0 + mrot[rb+4]*v1 + mrot[rb+5]*v2 + mpos[sb+1];
        float wz = mrot[rb+6]*v0 + mrot[rb+7]*v1 + mrot[rb+8]*v2 + mpos[sb+2];
        float cx = wx*cr[0] + wy*cr[3] + wz*cr[6] + cpx;
        float cy = wx*cr[1] + wy*cr[4] + wz*cr[7] + cpy;
        float cz = wx*cr[2] + wy*cr[5] + wz*cr[8] + cpz;
        sx[t] = cx / cz;  sy[t] = cy / cz;  sz[t] = cz;
    }
    __syncthreads();

    const int fb = (m*256 + t)*3;
    const int i0 = faces[fb+0], i1 = faces[fb+1], i2 = faces[fb+2];
    const float x0 = sx[i0], y0 = sy[i0], z0 = sz[i0];
    const float x1 = sx[i1], y1 = sy[i1], z1 = sz[i1];
    const float x2 = sx[i2], y2 = sy[i2], z2 = sz[i2];

    const int bf = b*NF + m*256 + t;
    float4* bboxp = ws;
    float4* geop  = ws + BF;
    float4* colp  = ws + 4*BF;

    bboxp[bf] = make_float4(fminf(fminf(x0,x1),x2), fminf(fminf(y0,y1),y2),
                            fmaxf(fmaxf(x0,x1),x2), fmaxf(fmaxf(y0,y1),y2));
    geop[bf*3+0] = make_float4(x0, y0, x1, y1);
    geop[bf*3+1] = make_float4(x2, y2, z0, z1);
    geop[bf*3+2] = make_float4(z2, 0.0f, 0.0f, 0.0f);

    int c0i = (m*256 + i0)*3, c1i = (m*256 + i1)*3, c2i = (m*256 + i2)*3;
    colp[bf*3+0] = make_float4(vcol[c0i], vcol[c0i+1], vcol[c0i+2], 0.0f);
    colp[bf*3+1] = make_float4(vcol[c1i], vcol[c1i+1], vcol[c1i+2], 0.0f);
    colp[bf*3+2] = make_float4(vcol[c2i], vcol[c2i+1], vcol[c2i+2], 0.0f);

    // conservative z lower bound: key = zmin - |grad z| * RM
    {
        float e1x = x1-x0, e1y = y1-y0, e2x = x2-x0, e2y = y2-y0;
        float rden = 1.0f / (e1x*e2y - e1y*e2x + 1e-12f);
        float dz1 = z1-z0, dz2 = z2-z0;
        float gx = (dz1*e2y - dz2*e1y) * rden;
        float gy = (dz2*e1x - dz1*e2x) * rden;
        float gmag = sqrtf(gx*gx + gy*gy);
        float zmin = fminf(fminf(z0, z1), z2);
        kraw[bf] = zmin - gmag * RM;
    }
}

// ============ kernel 1b: per-batch bitonic sort of faces by key ============
__global__ __launch_bounds__(512) void sort_kernel(
    const float* __restrict__ kraw, int* __restrict__ sfid,
    float* __restrict__ skey)
{
    const int b = blockIdx.x, t = threadIdx.x;
    __shared__ unsigned long long a[NF];
    {
        float k = kraw[b*NF + t];
        unsigned u = __float_as_uint(k);
        u ^= (u & 0x80000000u) ? 0xFFFFFFFFu : 0x80000000u;   // monotone map
        a[t] = ((unsigned long long)u << 32) | (unsigned)t;
    }
    __syncthreads();
    for (int kk = 2; kk <= NF; kk <<= 1) {
        for (int j = kk >> 1; j > 0; j >>= 1) {
            int l = t ^ j;
            if (l > t) {
                unsigned long long x = a[t], y = a[l];
                bool asc = ((t & kk) == 0);
                if ((asc && x > y) || (!asc && x < y)) { a[t] = y; a[l] = x; }
            }
            __syncthreads();
        }
    }
    int f = (int)(a[t] & 0xffffffffull);
    sfid[b*NF + t] = f;
    skey[b*NF + t] = kraw[b*NF + f];
}

// ============ kernel 2: tile binning in sorted order + chunk-min keys ============
__global__ __launch_bounds__(256) void bin_kernel(
    const float4* __restrict__ ws, const int* __restrict__ sfid,
    const float* __restrict__ skey, unsigned short* __restrict__ lists,
    float* __restrict__ ckey, int* __restrict__ cnts, int B)
{
    const int wid  = (blockIdx.x * 256 + threadIdx.x) >> 6;   // global wave id
    const int lane = threadIdx.x & 63;
    const int b = wid / NTILE, tile = wid % NTILE;
    const int ty = tile / TDIM, tx = tile % TDIM;
    const float x_lo = -1.0f + tx * (2.0f / TDIM);
    const float x_hi = x_lo + 2.0f / TDIM;
    const float y_hi = 1.0f - ty * (2.0f / TDIM);
    const float y_lo = y_hi - 2.0f / TDIM;

    const float4* bboxp = ws;
    unsigned short* list = lists + (size_t)wid * NF;
    int base = 0;
    #pragma unroll
    for (int k = 0; k < 8; ++k) {
        int rank = (k << 6) | lane;
        int f = sfid[b*NF + rank];
        float4 bb = bboxp[b*NF + f];
        bool hit = (bb.x - RM <= x_hi) && (bb.z + RM >= x_lo) &&
                   (bb.y - RM <= y_hi) && (bb.w + RM >= y_lo);
        unsigned long long m = __ballot(hit);
        if (hit) {
            int pos = base + __popcll(m & ((1ull << lane) - 1ull));
            list[pos] = (unsigned short)f;
            if ((pos & 63) == 0)
                ckey[wid*MAXC + (pos >> 6)] = skey[b*NF + rank];
        }
        base += __popcll(m);
    }
    if (lane == 0) cnts[wid] = base;
}

// ============ kernel 3: wave-per-pixel render, sorted scan + early exit ============
__global__ __launch_bounds__(256) void render_tile_kernel(
    const float4* __restrict__ ws, const unsigned short* __restrict__ lists,
    const float* __restrict__ ckey, const int* __restrict__ cnts,
    float* __restrict__ out, int B)
{
    const int wv   = threadIdx.x >> 6;              // 0..3
    const int lane = threadIdx.x & 63;
    const int blocksPerB = NTILE * 16;              // 16 blocks per tile (4 px each)
    const int b    = blockIdx.x / blocksPerB;
    const int rem  = blockIdx.x % blocksPerB;
    const int tile = rem >> 4, q = rem & 15;
    const int pit  = q * 4 + wv;                    // pixel-in-tile 0..63
    const int ty = tile / TDIM, tx = tile % TDIM;
    const int pi = ty * TSZ + (pit >> 3), pj = tx * TSZ + (pit & 7);
    const float px = ((float)pj + 0.5f) * (2.0f / WW) - 1.0f;
    const float py = 1.0f - ((float)pi + 0.5f) * (2.0f / HH);

    const int BF = B * NF;
    const float4* geop = ws + BF;
    const float4* colp = ws + 4*BF;
    const int wid = b*NTILE + tile;
    const unsigned short* list = lists + (size_t)wid * NF;
    const int L = cnts[wid];
    const int base = b * NF;

    // ---- prefetch all list chunks upfront (cheap u16 loads) ----
    int fid[MAXC];
    #pragma unroll
    for (int c = 0; c < MAXC; ++c) {
        fid[c] = -1;
        if (c * 64 < L) {
            int idx = c * 64 + lane;
            if (idx < L) fid[c] = (int)list[idx];
        }
    }

    // ---- sorted scan with provable early exit ----
    unsigned long long pk[MAXC];
    int validm = 0;
    int cend = 0;
    bool done = false;
    #pragma unroll
    for (int c = 0; c < MAXC; ++c) {
        pk[c] = SENT;
        if (c * 64 < L && !done) {
            if (c > 0) {
                // count accepted candidates strictly below the min key of the rest
                float keyc = ckey[wid*MAXC + c];
                int my = 0;
                #pragma unroll
                for (int s = 0; s < MAXC; ++s) {
                    if (s < c && (validm & (1 << s))) {
                        float zs = __uint_as_float((unsigned)(pk[s] >> 32));
                        my += (zs < keyc) ? 1 : 0;
                    }
                }
                #pragma unroll
                for (int m = 1; m < 64; m <<= 1) my += __shfl_xor(my, m, 64);
                if (my >= KK) done = true;
            }
            if (!done) {
                int fc = fid[c];
                int bf3 = (base + ((fc < 0) ? 0 : fc)) * 3;
                float4 g0 = geop[bf3+0], g1 = geop[bf3+1], g2 = geop[bf3+2];
                unsigned long long t = SENT;
                if (fc >= 0) {
                    Rast r = rasterize_g(px, py, g0, g1, g2);
                    if (r.zpix > 0.01f && r.dists <= BLUR_F) t = packzf(r.zpix, fc);
                }
                pk[c] = t;
                validm |= (t != SENT ? 1 : 0) << c;
                cend = c + 1;
            }
        }
    }

    const int c0 = __popc(validm);
    int cnt = c0;
    #pragma unroll
    for (int m = 1; m < 64; m <<= 1) cnt += __shfl_xor(cnt, m, 64);

    float nr = 0.0f, ng = 0.0f, nb = 0.0f, dn = 0.0f, ap = 1.0f;
    float zmaxv = EPS_F;

    if (cnt <= KK) {
        // ---- common path: all candidates included; zmax from butterfly min ----
        unsigned long long lmin = pk[0];
        #pragma unroll
        for (int c = 1; c < MAXC; ++c) lmin = (pk[c] < lmin) ? pk[c] : lmin;
        #pragma unroll
        for (int m = 1; m < 64; m <<= 1) {
            unsigned long long o2 = shflx64(lmin, m);
            lmin = (o2 < lmin) ? o2 : lmin;
        }
        if (cnt > 0) {
            float zming = __uint_as_float((unsigned)(lmin >> 32));
            zmaxv = fmaxf((ZFAR_F - zming) / (ZFAR_F - ZNEAR_F), EPS_F);
        }
        #pragma unroll
        for (int c = 0; c < MAXC; ++c)
            if (validm & (1 << c)) {
                int f = (int)(pk[c] & 0xffffffffull);
                float z = __uint_as_float((unsigned)(pk[c] >> 32));
                agg_face(px, py, geop, colp, base + f, z, zmaxv, nr, ng, nb, dn, ap);
            }
    } else if (cend == 1) {
        // ---- all candidates in chunk 0: bitonic sort ascending ----
        unsigned long long v = pk[0];
        #pragma unroll
        for (int kk = 2; kk <= 64; kk <<= 1) {
            #pragma unroll
            for (int j = kk >> 1; j > 0; j >>= 1) {
                unsigned long long o2 = shflx64(v, j);
                bool kmin = ((lane & kk) == 0) == ((lane & j) == 0);
                v = (kmin == (o2 < v)) ? o2 : v;
            }
        }
        unsigned z0b = (unsigned)__shfl((int)(unsigned)(v >> 32), 0, 64);
        zmaxv = fmaxf((ZFAR_F - __uint_as_float(z0b)) / (ZFAR_F - ZNEAR_F), EPS_F);
        if (lane < KK) {                             // cnt > 16 => all 16 valid
            int f = (int)(v & 0xffffffffull);
            float z = __uint_as_float((unsigned)(v >> 32));
            agg_face(px, py, geop, colp, base + f, z, zmaxv, nr, ng, nb, dn, ap);
        }
    } else {
        // ---- multi-chunk & cnt>16 -> pop-min 16 rounds ----
        int remm = validm, inclm = 0;
        float zming = 0.0f;
        for (int r = 0; r < KK; ++r) {
            unsigned long long lm = SENT;
            #pragma unroll
            for (int k = 0; k < MAXC; ++k)
                if (remm & (1 << k)) lm = (pk[k] < lm) ? pk[k] : lm;
            #pragma unroll
            for (int m = 1; m < 64; m <<= 1) {
                unsigned long long o2 = shflx64(lm, m);
                lm = (o2 < lm) ? o2 : lm;
            }
            if (r == 0) zming = __uint_as_float((unsigned)(lm >> 32));
            #pragma unroll
            for (int k = 0; k < MAXC; ++k)
                if ((remm & (1 << k)) && pk[k] == lm) { inclm |= 1 << k; remm &= ~(1 << k); }
        }
        zmaxv = fmaxf((ZFAR_F - zming) / (ZFAR_F - ZNEAR_F), EPS_F);
        #pragma unroll
        for (int k = 0; k < MAXC; ++k)
            if (inclm & (1 << k)) {
                int f = (int)(pk[k] & 0xffffffffull);
                float z = __uint_as_float((unsigned)(pk[k] >> 32));
                agg_face(px, py, geop, colp, base + f, z, zmaxv, nr, ng, nb, dn, ap);
            }
    }

    // ---- wave butterfly reductions (deterministic fixed order) ----
    #pragma unroll
    for (int m = 1; m < 64; m <<= 1) {
        nr += __shfl_xor(nr, m, 64);
        ng += __shfl_xor(ng, m, 64);
        nb += __shfl_xor(nb, m, 64);
        dn += __shfl_xor(dn, m, 64);
        ap *= __shfl_xor(ap, m, 64);
    }
    if (lane == 0) {
        float delta = __expf((EPS_F - zmaxv) / GAMMA_F);
        float dd = dn + delta;
        float4 o4;
        o4.x = (nr + delta) / dd;
        o4.y = (ng + delta) / dd;
        o4.z = (nb + delta) / dd;
        o4.w = 1.0f - ap;
        *reinterpret_cast<float4*>(&out[((size_t)b * NPIX + pi * WW + pj) * 4]) = o4;
    }
}

// ============ fallback: round-6 wave-per-pixel kernel (no binning) ============
__global__ __launch_bounds__(256) void render_wave_kernel(
    const float4* __restrict__ ws, float* __restrict__ out, int B)
{
    const int tilesPerB = NPIX / 4;
    const int b    = blockIdx.x / tilesPerB;
    const int tile = blockIdx.x % tilesPerB;
    const int wv   = threadIdx.x >> 6;
    const int lane = threadIdx.x & 63;
    const int p    = tile*4 + wv;
    const int pi = p / WW, pj = p % WW;
    const float px = ((float)pj + 0.5f) * 2.0f / (float)WW - 1.0f;
    const float py = 1.0f - ((float)pi + 0.5f) * 2.0f / (float)HH;

    const int BF = B * NF;
    const float4* bboxp = ws;
    const float4* geop  = ws + BF;
    const float4* colp  = ws + 4*BF;
    const int base = b * NF;

    unsigned long long pk[8];
    int validm = 0;
    #pragma unroll
    for (int k = 0; k < 8; ++k) {
        int f  = (k << 6) | lane;
        int bf = base + f;
        float4 bb = bboxp[bf];
        unsigned long long t = SENT;
        if (px >= bb.x - RM && px <= bb.z + RM &&
            py >= bb.y - RM && py <= bb.w + RM) {
            float4 g0 = geop[bf*3+0], g1 = geop[bf*3+1], g2 = geop[bf*3+2];
            Rast r = rasterize_g(px, py, g0, g1, g2);
            if (r.zpix > 0.01f && r.dists <= BLUR_F) t = packzf(r.zpix, f);
        }
        pk[k] = t;
        validm |= (t != SENT ? 1 : 0) << k;
    }

    const int c0 = __popc(validm);
    int cnt = c0;
    #pragma unroll
    for (int m = 1; m < 64; m <<= 1) cnt += __shfl_xor(cnt, m, 64);

    float nr = 0.0f, ng = 0.0f, nb = 0.0f, dn = 0.0f, ap = 1.0f;
    float zmaxv = EPS_F;

    if (cnt <= KK) {
        unsigned long long lmin = pk[0];
        #pragma unroll
        for (int c = 1; c < 8; ++c) lmin = (pk[c] < lmin) ? pk[c] : lmin;
        #pragma unroll
        for (int m = 1; m < 64; m <<= 1) {
            unsigned long long o2 = shflx64(lmin, m);
            lmin = (o2 < lmin) ? o2 : lmin;
        }
        if (cnt > 0) {
            float zming = __uint_as_float((unsigned)(lmin >> 32));
            zmaxv = fmaxf((ZFAR_F - zming) / (ZFAR_F - ZNEAR_F), EPS_F);
        }
        #pragma unroll
        for (int c = 0; c < 8; ++c)
            if (validm & (1 << c)) {
                int f = (int)(pk[c] & 0xffffffffull);
                float z = __uint_as_float((unsigned)(pk[c] >> 32));
                agg_face(px, py, geop, colp, base + f, z, zmaxv, nr, ng, nb, dn, ap);
            }
    } else {
        int remm = validm, inclm = 0;
        float zming = 0.0f;
        for (int r = 0; r < KK; ++r) {
            unsigned long long lm = SENT;
            #pragma unroll
            for (int k = 0; k < 8; ++k)
                if (remm & (1 << k)) lm = (pk[k] < lm) ? pk[k] : lm;
            #pragma unroll
            for (int m = 1; m < 64; m <<= 1) {
                unsigned long long o2 = shflx64(lm, m);
                lm = (o2 < lm) ? o2 : lm;
            }
            if (r == 0) zming = __uint_as_float((unsigned)(lm >> 32));
            #pragma unroll
            for (int k = 0; k < 8; ++k)
                if ((remm & (1 << k)) && pk[k] == lm) { inclm |= 1 << k; remm &= ~(1 << k); }
        }
        zmaxv = fmaxf((ZFAR_F - zming) / (ZFAR_F - ZNEAR_F), EPS_F);
        #pragma unroll
        for (int k = 0; k < 8; ++k)
            if (inclm & (1 << k)) {
                int f = (int)(pk[k] & 0xffffffffull);
                float z = __uint_as_float((unsigned)(pk[k] >> 32));
                agg_face(px, py, geop, colp, base + f, z, zmaxv, nr, ng, nb, dn, ap);
            }
    }

    #pragma unroll
    for (int m = 1; m < 64; m <<= 1) {
        nr += __shfl_xor(nr, m, 64);
        ng += __shfl_xor(ng, m, 64);
        nb += __shfl_xor(nb, m, 64);
        dn += __shfl_xor(dn, m, 64);
        ap *= __shfl_xor(ap, m, 64);
    }
    if (lane == 0) {
        float delta = __expf((EPS_F - zmaxv) / GAMMA_F);
        float dd = dn + delta;
        float4 o4;
        o4.x = (nr + delta) / dd;
        o4.y = (ng + delta) / dd;
        o4.z = (nb + delta) / dd;
        o4.w = 1.0f - ap;
        *reinterpret_cast<float4*>(&out[((size_t)b * NPIX + p) * 4]) = o4;
    }
}

extern "C" void kernel_launch(void* const* d_in, const int* in_sizes, int n_in,
                              void* d_out, int out_size, void* d_ws, size_t ws_size,
                              hipStream_t stream) {
    const float* mpos   = (const float*)d_in[0];
    const float* mrot   = (const float*)d_in[1];
    const float* mscale = (const float*)d_in[2];
    const float* cpos   = (const float*)d_in[3];
    const float* crot   = (const float*)d_in[4];
    const float* verts  = (const float*)d_in[5];
    const int*   faces  = (const int*)d_in[6];
    const float* vcol   = (const float*)d_in[7];
    float*       out    = (float*)d_out;

    const int B  = in_sizes[3] / 3;                 // cam_pos is (B,3)
    const int BF = B * NF;
    const size_t base_bytes  = (size_t)BF * 7 * sizeof(float4);      // bbox+geo+col
    const size_t kraw_bytes  = (size_t)BF * sizeof(float);
    const size_t sfid_bytes  = (size_t)BF * sizeof(int);
    const size_t skey_bytes  = (size_t)BF * sizeof(float);
    const size_t lists_bytes = (size_t)B * NTILE * NF * sizeof(unsigned short);
    const size_t ckey_bytes  = (size_t)B * NTILE * MAXC * sizeof(float);
    const size_t cnts_bytes  = (size_t)B * NTILE * sizeof(int);
    const size_t need_full   = base_bytes + kraw_bytes + sfid_bytes + skey_bytes
                             + lists_bytes + ckey_bytes + cnts_bytes;

    float4* wsf = (float4*)d_ws;
    char* p = (char*)d_ws + base_bytes;
    float* kraw = (float*)p;                 p += kraw_bytes;
    int*   sfid = (int*)p;                   p += sfid_bytes;
    float* skey = (float*)p;                 p += skey_bytes;
    unsigned short* lists = (unsigned short*)p;  p += lists_bytes;
    float* ckey = (float*)p;                 p += ckey_bytes;
    int*   cnts = (int*)p;

    if (ws_size >= need_full) {
        stage_kernel<<<dim3(B * MM), dim3(256), 0, stream>>>(
            mpos, mrot, mscale, cpos, crot, verts, faces, vcol, wsf, kraw);
        sort_kernel<<<dim3(B), dim3(512), 0, stream>>>(kraw, sfid, skey);
        bin_kernel<<<dim3((B * NTILE) / 4), dim3(256), 0, stream>>>(
            wsf, sfid, skey, lists, ckey, cnts, B);
        render_tile_kernel<<<dim3(B * NTILE * 16), dim3(256), 0, stream>>>(
            wsf, lists, ckey, cnts, out, B);
    } else {
        stage_kernel<<<dim3(B * MM), dim3(256), 0, stream>>>(
            mpos, mrot, mscale, cpos, crot, verts, faces, vcol, wsf, kraw);
        render_wave_kernel<<<dim3(B * (NPIX / 4)), dim3(256), 0, stream>>>(
            wsf, out, B);
    }
}

// Round 10
// 45.820 us; speedup vs baseline: 1.1794x; 1.1794x over previous
//
#include <hip/hip_runtime.h>

#pragma clang fp contract(off)

#define HH 96
#define WW 96
#define KK 16
#define MM 2
#define NF 512            // M * Fm
#define NPIX (HH*WW)      // 9216
#define TDIM 12           // tiles per side
#define TSZ 8             // pixels per tile side
#define NTILE (TDIM*TDIM) // 144
#define MAXC 8            // max list chunks (NF/64)

#define SIGMA_F 1e-4f
#define GAMMA_F 1e-4f
#define BLUR_F  9.210240366975851e-4f   // log(1/1e-4 - 1) * 1e-4 -> f32
#define EPS_F   1e-10f
#define ZFAR_F  100.0f
#define ZNEAR_F 1.0f
#define RM      0.0304f                 // > sqrt(BLUR_F) = 0.0303484

#define SENT 0xFFFFFFFFFFFFFFFFull

__device__ __forceinline__ float frcp(float x) { return __builtin_amdgcn_rcpf(x); }

__device__ __forceinline__ float edge_d2(float px, float py,
                                         float ax, float ay,
                                         float bx, float by) {
    float abx = bx - ax, aby = by - ay;
    float apx = px - ax, apy = py - ay;
    float t = (apx*abx + apy*aby) * frcp(abx*abx + aby*aby + 1e-12f);
    t = fminf(fmaxf(t, 0.0f), 1.0f);
    float dx = apx - t*abx, dy = apy - t*aby;
    return dx*dx + dy*dy;
}

struct Rast { float b0, b1, b2, zpix, dists; };

__device__ __forceinline__ Rast rasterize_s(float px, float py,
                                            float v0x, float v0y, float v1x, float v1y,
                                            float v2x, float v2y,
                                            float z0, float z1, float z2) {
    Rast r;
    float e1x=v1x-v0x, e1y=v1y-v0y, e2x=v2x-v0x, e2y=v2y-v0y;
    float dx=px-v0x, dy=py-v0y;
    float rden = frcp(e1x*e2y - e1y*e2x + 1e-12f);
    r.b1 = (dx*e2y - dy*e2x) * rden;
    r.b2 = (e1x*dy - e1y*dx) * rden;
    r.b0 = 1.0f - r.b1 - r.b2;
    r.zpix = r.b0*z0 + r.b1*z1 + r.b2*z2;
    bool inside = (r.b0 >= 0.0f) && (r.b1 >= 0.0f) && (r.b2 >= 0.0f);
    float d2 = edge_d2(px, py, v0x, v0y, v1x, v1y);
    d2 = fminf(d2, edge_d2(px, py, v1x, v1y, v2x, v2y));
    d2 = fminf(d2, edge_d2(px, py, v2x, v2y, v0x, v0y));
    r.dists = inside ? -d2 : d2;
    return r;
}

// geo-packed layout: g0=(x0,y0,x1,y1) g1=(x2,y2,z0,z1) g2=(z2,-,-,-)
__device__ __forceinline__ Rast rasterize_g(float px, float py,
                                            float4 g0, float4 g1, float4 g2) {
    return rasterize_s(px, py, g0.x, g0.y, g0.z, g0.w, g1.x, g1.y,
                       g1.z, g1.w, g2.x);
}

__device__ __forceinline__ unsigned long long packzf(float z, int f) {
    return (((unsigned long long)__float_as_uint(z)) << 32) | (unsigned int)f;
}

__device__ __forceinline__ unsigned long long shflx64(unsigned long long v, int m) {
    int lo = __shfl_xor((int)(unsigned)(v & 0xffffffffull), m, 64);
    int hi = __shfl_xor((int)(unsigned)(v >> 32), m, 64);
    return ((unsigned long long)(unsigned)hi << 32) | (unsigned)lo;
}

__device__ __forceinline__ void agg_face(float px, float py,
                                         const float4* __restrict__ geop,
                                         const float4* __restrict__ colp,
                                         int bf, float z, float zmaxv,
                                         float& nr, float& ng, float& nb,
                                         float& dn, float& ap) {
    float4 g0 = geop[bf*3+0], g1 = geop[bf*3+1], g2 = geop[bf*3+2];
    float4 c0 = colp[bf*3+0], c1 = colp[bf*3+1], c2 = colp[bf*3+2];
    Rast r = rasterize_g(px, py, g0, g1, g2);
    float prob = frcp(1.0f + __expf(r.dists / SIGMA_F));
    float zinv = (ZFAR_F - z) / (ZFAR_F - ZNEAR_F);
    float w = prob * __expf((zinv - zmaxv) / GAMMA_F);
    nr += w * (r.b0*c0.x + r.b1*c1.x + r.b2*c2.x);
    ng += w * (r.b0*c0.y + r.b1*c1.y + r.b2*c2.y);
    nb += w * (r.b0*c0.z + r.b1*c1.z + r.b2*c2.z);
    dn += w;
    ap *= (1.0f - prob);
}

// ============ kernel 1: stage per-(b,face) bbox/geo/col records ============
__global__ void stage_kernel(
    const float* __restrict__ mpos, const float* __restrict__ mrot,
    const float* __restrict__ mscale, const float* __restrict__ cpos,
    const float* __restrict__ crot, const float* __restrict__ verts,
    const int* __restrict__ faces, const float* __restrict__ vcol,
    float4* __restrict__ ws)
{
    const int b = blockIdx.x / MM, m = blockIdx.x % MM, t = threadIdx.x;
    const int B = gridDim.x / MM;
    const int BF = B * NF;
    __shared__ float sx[256], sy[256], sz[256];

    float cr[9];
    #pragma unroll
    for (int i = 0; i < 9; ++i) cr[i] = crot[b*9 + i];
    const float cpx = cpos[b*3+0], cpy = cpos[b*3+1], cpz = cpos[b*3+2];

    {
        int sb = (b*MM + m)*3, rb = (b*MM + m)*9;
        int vid = m*256 + t;
        float v0 = verts[vid*3+0] * mscale[sb+0];
        float v1 = verts[vid*3+1] * mscale[sb+1];
        float v2 = verts[vid*3+2] * mscale[sb+2];
        float wx = mrot[rb+0]*v0 + mrot[rb+1]*v1 + mrot[rb+2]*v2 + mpos[sb+0];
        float wy = mrot[rb+3]*v0 + mrot[rb+4]*v1 + mrot[rb+5]*v2 + mpos[sb+1];
        float wz = mrot[rb+6]*v0 + mrot[rb+7]*v1 + mrot[rb+8]*v2 + mpos[sb+2];
        float cx = wx*cr[0] + wy*cr[3] + wz*cr[6] + cpx;
        float cy = wx*cr[1] + wy*cr[4] + wz*cr[7] + cpy;
        float cz = wx*cr[2] + wy*cr[5] + wz*cr[8] + cpz;
        sx[t] = cx / cz;  sy[t] = cy / cz;  sz[t] = cz;
    }
    __syncthreads();

    const int fb = (m*256 + t)*3;
    const int i0 = faces[fb+0], i1 = faces[fb+1], i2 = faces[fb+2];
    const float x0 = sx[i0], y0 = sy[i0], z0 = sz[i0];
    const float x1 = sx[i1], y1 = sy[i1], z1 = sz[i1];
    const float x2 = sx[i2], y2 = sy[i2], z2 = sz[i2];

    const int bf = b*NF + m*256 + t;
    float4* bboxp = ws;
    float4* geop  = ws + BF;
    float4* colp  = ws + 4*BF;

    bboxp[bf] = make_float4(fminf(fminf(x0,x1),x2), fminf(fminf(y0,y1),y2),
                            fmaxf(fmaxf(x0,x1),x2), fmaxf(fmaxf(y0,y1),y2));
    geop[bf*3+0] = make_float4(x0, y0, x1, y1);
    geop[bf*3+1] = make_float4(x2, y2, z0, z1);
    geop[bf*3+2] = make_float4(z2, 0.0f, 0.0f, 0.0f);

    int c0i = (m*256 + i0)*3, c1i = (m*256 + i1)*3, c2i = (m*256 + i2)*3;
    colp[bf*3+0] = make_float4(vcol[c0i], vcol[c0i+1], vcol[c0i+2], 0.0f);
    colp[bf*3+1] = make_float4(vcol[c1i], vcol[c1i+1], vcol[c1i+2], 0.0f);
    colp[bf*3+2] = make_float4(vcol[c2i], vcol[c2i+1], vcol[c2i+2], 0.0f);
}

// ============ kernel 2: deterministic tile binning (1 wave per (b,tile)) ============
__global__ __launch_bounds__(256) void bin_kernel(
    const float4* __restrict__ ws, unsigned short* __restrict__ lists,
    int* __restrict__ cnts, int B)
{
    const int wid  = (blockIdx.x * 256 + threadIdx.x) >> 6;   // global wave id
    const int lane = threadIdx.x & 63;
    if (wid >= B * NTILE) return;
    const int b = wid / NTILE, tile = wid % NTILE;
    const int ty = tile / TDIM, tx = tile % TDIM;
    const float x_lo = -1.0f + tx * (2.0f / TDIM);
    const float x_hi = x_lo + 2.0f / TDIM;
    const float y_hi = 1.0f - ty * (2.0f / TDIM);
    const float y_lo = y_hi - 2.0f / TDIM;

    const float4* bboxp = ws;
    unsigned short* list = lists + (size_t)wid * NF;
    int base = 0;
    #pragma unroll
    for (int k = 0; k < 8; ++k) {
        int f = (k << 6) | lane;
        float4 bb = bboxp[b*NF + f];
        bool hit = (bb.x - RM <= x_hi) && (bb.z + RM >= x_lo) &&
                   (bb.y - RM <= y_hi) && (bb.w + RM >= y_lo);
        unsigned long long m = __ballot(hit);
        if (hit) {
            int rank = __popcll(m & ((1ull << lane) - 1ull));
            list[base + rank] = (unsigned short)f;       // ascending f order
        }
        base += __popcll(m);
    }
    if (lane == 0) cnts[wid] = base;
}

// ============ kernel 3: wave-per-pixel render, block-shared LDS staging ============
__global__ __launch_bounds__(256) void render_tile_kernel(
    const float4* __restrict__ ws, const unsigned short* __restrict__ lists,
    const int* __restrict__ cnts, float* __restrict__ out, int B)
{
    const int wv   = threadIdx.x >> 6;              // 0..3
    const int lane = threadIdx.x & 63;
    const int blocksPerB = NTILE * 16;              // 16 blocks per tile (4 px each)
    const int b    = blockIdx.x / blocksPerB;
    const int rem  = blockIdx.x % blocksPerB;
    const int tile = rem >> 4, q = rem & 15;
    const int pit  = q * 4 + wv;                    // pixel-in-tile 0..63
    const int ty = tile / TDIM, tx = tile % TDIM;
    const int pi = ty * TSZ + (pit >> 3), pj = tx * TSZ + (pit & 7);
    const float px = ((float)pj + 0.5f) * (2.0f / WW) - 1.0f;
    const float py = 1.0f - ((float)pi + 0.5f) * (2.0f / HH);

    const int BF = B * NF;
    const float4* geop = ws + BF;
    const float4* colp = ws + 4*BF;
    const int wid = b*NTILE + tile;
    const unsigned short* list = lists + (size_t)wid * NF;
    const int L = cnts[wid];                         // block-uniform
    const int base = b * NF;

    // SoA double-buffered face cache: comp 0..8 = x0,y0,x1,y1,x2,y2,z0,z1,z2
    __shared__ float sg[2][9][64];
    __shared__ int   sf[2][64];

    const int j    = threadIdx.x & 63;               // staging face slot
    const int part = threadIdx.x >> 6;               // 0..3

#define STAGE(cc, bb) do { \
        int idx_ = (cc)*64 + j; \
        int f_ = (idx_ < L) ? (int)list[idx_] : -1; \
        int bf3_ = (base + ((f_ < 0) ? 0 : f_)) * 3; \
        if (part == 0) { \
            sf[bb][j] = f_; \
            float4 g_ = geop[bf3_ + 0]; \
            sg[bb][0][j] = g_.x; sg[bb][1][j] = g_.y; \
            sg[bb][2][j] = g_.z; sg[bb][3][j] = g_.w; \
        } else if (part == 1) { \
            float4 g_ = geop[bf3_ + 1]; \
            sg[bb][4][j] = g_.x; sg[bb][5][j] = g_.y; \
            sg[bb][6][j] = g_.z; sg[bb][7][j] = g_.w; \
        } else if (part == 2) { \
            float4 g_ = geop[bf3_ + 2]; \
            sg[bb][8][j] = g_.x; \
        } \
    } while (0)

    unsigned long long pk[MAXC];
    int validm = 0;

    if (L > 0) {
        STAGE(0, 0);
        __syncthreads();
    }

    #pragma unroll
    for (int c = 0; c < MAXC; ++c) {
        pk[c] = SENT;
        if (c * 64 < L) {                            // block-uniform
            const int bb = c & 1;
            if ((c + 1) * 64 < L) STAGE(c + 1, (c + 1) & 1);
            // consume chunk c from LDS (lane-indexed, stride-4B: conflict-free)
            int fc = sf[bb][lane];
            float x0 = sg[bb][0][lane], y0 = sg[bb][1][lane];
            float x1 = sg[bb][2][lane], y1 = sg[bb][3][lane];
            float x2 = sg[bb][4][lane], y2 = sg[bb][5][lane];
            float z0 = sg[bb][6][lane], z1 = sg[bb][7][lane];
            float z2 = sg[bb][8][lane];
            unsigned long long t = SENT;
            if (fc >= 0) {
                Rast r = rasterize_s(px, py, x0, y0, x1, y1, x2, y2, z0, z1, z2);
                if (r.zpix > 0.01f && r.dists <= BLUR_F) t = packzf(r.zpix, fc);
            }
            pk[c] = t;
            validm |= (t != SENT ? 1 : 0) << c;
            __syncthreads();
        }
    }
#undef STAGE

    const int c0 = __popc(validm);
    int cnt = c0;
    #pragma unroll
    for (int m = 1; m < 64; m <<= 1) cnt += __shfl_xor(cnt, m, 64);

    float nr = 0.0f, ng = 0.0f, nb = 0.0f, dn = 0.0f, ap = 1.0f;
    float zmaxv = EPS_F;

    if (cnt <= KK) {
        // ---- common path: all candidates included; zmax from butterfly min ----
        unsigned long long lmin = pk[0];
        #pragma unroll
        for (int c = 1; c < MAXC; ++c) lmin = (pk[c] < lmin) ? pk[c] : lmin;
        #pragma unroll
        for (int m = 1; m < 64; m <<= 1) {
            unsigned long long o2 = shflx64(lmin, m);
            lmin = (o2 < lmin) ? o2 : lmin;
        }
        if (cnt > 0) {
            float zming = __uint_as_float((unsigned)(lmin >> 32));
            zmaxv = fmaxf((ZFAR_F - zming) / (ZFAR_F - ZNEAR_F), EPS_F);
        }
        #pragma unroll
        for (int c = 0; c < MAXC; ++c)
            if (validm & (1 << c)) {
                int f = (int)(pk[c] & 0xffffffffull);
                float z = __uint_as_float((unsigned)(pk[c] >> 32));
                agg_face(px, py, geop, colp, base + f, z, zmaxv, nr, ng, nb, dn, ap);
            }
    } else if (L <= 64) {
        // ---- single-chunk sort path: bitonic ascending on registers ----
        unsigned long long v = pk[0];
        #pragma unroll
        for (int kk = 2; kk <= 64; kk <<= 1) {
            #pragma unroll
            for (int jj = kk >> 1; jj > 0; jj >>= 1) {
                unsigned long long o2 = shflx64(v, jj);
                bool kmin = ((lane & kk) == 0) == ((lane & jj) == 0);
                v = (kmin == (o2 < v)) ? o2 : v;
            }
        }
        unsigned z0b = (unsigned)__shfl((int)(unsigned)(v >> 32), 0, 64);
        zmaxv = fmaxf((ZFAR_F - __uint_as_float(z0b)) / (ZFAR_F - ZNEAR_F), EPS_F);
        if (lane < KK) {                             // cnt > 16 => all 16 valid
            int f = (int)(v & 0xffffffffull);
            float z = __uint_as_float((unsigned)(v >> 32));
            agg_face(px, py, geop, colp, base + f, z, zmaxv, nr, ng, nb, dn, ap);
        }
    } else {
        // ---- multi-chunk & cnt>16 -> pop-min 16 rounds ----
        int remm = validm, inclm = 0;
        float zming = 0.0f;
        for (int r = 0; r < KK; ++r) {
            unsigned long long lm = SENT;
            #pragma unroll
            for (int k = 0; k < MAXC; ++k)
                if (remm & (1 << k)) lm = (pk[k] < lm) ? pk[k] : lm;
            #pragma unroll
            for (int m = 1; m < 64; m <<= 1) {
                unsigned long long o2 = shflx64(lm, m);
                lm = (o2 < lm) ? o2 : lm;
            }
            if (r == 0) zming = __uint_as_float((unsigned)(lm >> 32));
            #pragma unroll
            for (int k = 0; k < MAXC; ++k)
                if ((remm & (1 << k)) && pk[k] == lm) { inclm |= 1 << k; remm &= ~(1 << k); }
        }
        zmaxv = fmaxf((ZFAR_F - zming) / (ZFAR_F - ZNEAR_F), EPS_F);
        #pragma unroll
        for (int k = 0; k < MAXC; ++k)
            if (inclm & (1 << k)) {
                int f = (int)(pk[k] & 0xffffffffull);
                float z = __uint_as_float((unsigned)(pk[k] >> 32));
                agg_face(px, py, geop, colp, base + f, z, zmaxv, nr, ng, nb, dn, ap);
            }
    }

    // ---- wave butterfly reductions (deterministic fixed order) ----
    #pragma unroll
    for (int m = 1; m < 64; m <<= 1) {
        nr += __shfl_xor(nr, m, 64);
        ng += __shfl_xor(ng, m, 64);
        nb += __shfl_xor(nb, m, 64);
        dn += __shfl_xor(dn, m, 64);
        ap *= __shfl_xor(ap, m, 64);
    }
    if (lane == 0) {
        float delta = __expf((EPS_F - zmaxv) / GAMMA_F);
        float dd = dn + delta;
        float4 o4;
        o4.x = (nr + delta) / dd;
        o4.y = (ng + delta) / dd;
        o4.z = (nb + delta) / dd;
        o4.w = 1.0f - ap;
        *reinterpret_cast<float4*>(&out[((size_t)b * NPIX + pi * WW + pj) * 4]) = o4;
    }
}

// ============ fallback: round-6 wave-per-pixel kernel (no binning) ============
__global__ __launch_bounds__(256) void render_wave_kernel(
    const float4* __restrict__ ws, float* __restrict__ out, int B)
{
    const int tilesPerB = NPIX / 4;
    const int b    = blockIdx.x / tilesPerB;
    const int tile = blockIdx.x % tilesPerB;
    const int wv   = threadIdx.x >> 6;
    const int lane = threadIdx.x & 63;
    const int p    = tile*4 + wv;
    const int pi = p / WW, pj = p % WW;
    const float px = ((float)pj + 0.5f) * 2.0f / (float)WW - 1.0f;
    const float py = 1.0f - ((float)pi + 0.5f) * 2.0f / (float)HH;

    const int BF = B * NF;
    const float4* bboxp = ws;
    const float4* geop  = ws + BF;
    const float4* colp  = ws + 4*BF;
    const int base = b * NF;

    unsigned long long pk[8];
    int validm = 0;
    #pragma unroll
    for (int k = 0; k < 8; ++k) {
        int f  = (k << 6) | lane;
        int bf = base + f;
        float4 bb = bboxp[bf];
        unsigned long long t = SENT;
        if (px >= bb.x - RM && px <= bb.z + RM &&
            py >= bb.y - RM && py <= bb.w + RM) {
            float4 g0 = geop[bf*3+0], g1 = geop[bf*3+1], g2 = geop[bf*3+2];
            Rast r = rasterize_g(px, py, g0, g1, g2);
            if (r.zpix > 0.01f && r.dists <= BLUR_F) t = packzf(r.zpix, f);
        }
        pk[k] = t;
        validm |= (t != SENT ? 1 : 0) << k;
    }

    const int c0 = __popc(validm);
    int cnt = c0;
    #pragma unroll
    for (int m = 1; m < 64; m <<= 1) cnt += __shfl_xor(cnt, m, 64);

    float nr = 0.0f, ng = 0.0f, nb = 0.0f, dn = 0.0f, ap = 1.0f;
    float zmaxv = EPS_F;

    if (cnt <= KK) {
        unsigned long long lmin = pk[0];
        #pragma unroll
        for (int c = 1; c < 8; ++c) lmin = (pk[c] < lmin) ? pk[c] : lmin;
        #pragma unroll
        for (int m = 1; m < 64; m <<= 1) {
            unsigned long long o2 = shflx64(lmin, m);
            lmin = (o2 < lmin) ? o2 : lmin;
        }
        if (cnt > 0) {
            float zming = __uint_as_float((unsigned)(lmin >> 32));
            zmaxv = fmaxf((ZFAR_F - zming) / (ZFAR_F - ZNEAR_F), EPS_F);
        }
        #pragma unroll
        for (int c = 0; c < 8; ++c)
            if (validm & (1 << c)) {
                int f = (int)(pk[c] & 0xffffffffull);
                float z = __uint_as_float((unsigned)(pk[c] >> 32));
                agg_face(px, py, geop, colp, base + f, z, zmaxv, nr, ng, nb, dn, ap);
            }
    } else {
        int remm = validm, inclm = 0;
        float zming = 0.0f;
        for (int r = 0; r < KK; ++r) {
            unsigned long long lm = SENT;
            #pragma unroll
            for (int k = 0; k < 8; ++k)
                if (remm & (1 << k)) lm = (pk[k] < lm) ? pk[k] : lm;
            #pragma unroll
            for (int m = 1; m < 64; m <<= 1) {
                unsigned long long o2 = shflx64(lm, m);
                lm = (o2 < lm) ? o2 : lm;
            }
            if (r == 0) zming = __uint_as_float((unsigned)(lm >> 32));
            #pragma unroll
            for (int k = 0; k < 8; ++k)
                if ((remm & (1 << k)) && pk[k] == lm) { inclm |= 1 << k; remm &= ~(1 << k); }
        }
        zmaxv = fmaxf((ZFAR_F - zming) / (ZFAR_F - ZNEAR_F), EPS_F);
        #pragma unroll
        for (int k = 0; k < 8; ++k)
            if (inclm & (1 << k)) {
                int f = (int)(pk[k] & 0xffffffffull);
                float z = __uint_as_float((unsigned)(pk[k] >> 32));
                agg_face(px, py, geop, colp, base + f, z, zmaxv, nr, ng, nb, dn, ap);
            }
    }

    #pragma unroll
    for (int m = 1; m < 64; m <<= 1) {
        nr += __shfl_xor(nr, m, 64);
        ng += __shfl_xor(ng, m, 64);
        nb += __shfl_xor(nb, m, 64);
        dn += __shfl_xor(dn, m, 64);
        ap *= __shfl_xor(ap, m, 64);
    }
    if (lane == 0) {
        float delta = __expf((EPS_F - zmaxv) / GAMMA_F);
        float dd = dn + delta;
        float4 o4;
        o4.x = (nr + delta) / dd;
        o4.y = (ng + delta) / dd;
        o4.z = (nb + delta) / dd;
        o4.w = 1.0f - ap;
        *reinterpret_cast<float4*>(&out[((size_t)b * NPIX + p) * 4]) = o4;
    }
}

extern "C" void kernel_launch(void* const* d_in, const int* in_sizes, int n_in,
                              void* d_out, int out_size, void* d_ws, size_t ws_size,
                              hipStream_t stream) {
    const float* mpos   = (const float*)d_in[0];
    const float* mrot   = (const float*)d_in[1];
    const float* mscale = (const float*)d_in[2];
    const float* cpos   = (const float*)d_in[3];
    const float* crot   = (const float*)d_in[4];
    const float* verts  = (const float*)d_in[5];
    const int*   faces  = (const int*)d_in[6];
    const float* vcol   = (const float*)d_in[7];
    float*       out    = (float*)d_out;

    const int B  = in_sizes[3] / 3;                 // cam_pos is (B,3)
    const int BF = B * NF;
    const size_t base_bytes  = (size_t)BF * 7 * sizeof(float4);      // bbox+geo+col
    const size_t lists_bytes = (size_t)B * NTILE * NF * sizeof(unsigned short);
    const size_t cnts_bytes  = (size_t)B * NTILE * sizeof(int);
    const size_t need_full   = base_bytes + lists_bytes + cnts_bytes;

    float4* wsf = (float4*)d_ws;
    if (ws_size >= need_full) {
        unsigned short* lists = (unsigned short*)((char*)d_ws + base_bytes);
        int* cnts = (int*)((char*)d_ws + base_bytes + lists_bytes);
        stage_kernel<<<dim3(B * MM), dim3(256), 0, stream>>>(
            mpos, mrot, mscale, cpos, crot, verts, faces, vcol, wsf);
        bin_kernel<<<dim3((B * NTILE + 3) / 4), dim3(256), 0, stream>>>(
            wsf, lists, cnts, B);
        render_tile_kernel<<<dim3(B * NTILE * 16), dim3(256), 0, stream>>>(
            wsf, lists, cnts, out, B);
    } else {
        stage_kernel<<<dim3(B * MM), dim3(256), 0, stream>>>(
            mpos, mrot, mscale, cpos, crot, verts, faces, vcol, wsf);
        render_wave_kernel<<<dim3(B * (NPIX / 4)), dim3(256), 0, stream>>>(
            wsf, out, B);
    }
}

// Round 11
// 45.146 us; speedup vs baseline: 1.1970x; 1.0149x over previous
//
#include <hip/hip_runtime.h>

#pragma clang fp contract(off)

#define HH 96
#define WW 96
#define KK 16
#define MM 2
#define NF 512            // M * Fm
#define NV 512            // M * V
#define NPIX (HH*WW)      // 9216
#define TDIM 12           // tiles per side
#define TSZ 8             // pixels per tile side
#define NTILE (TDIM*TDIM) // 144
#define MAXC 8            // max list chunks (NF/64)
#define BPT 8             // blocks per tile (8 px each)

#define SIGMA_F 1e-4f
#define GAMMA_F 1e-4f
#define BLUR_F  9.210240366975851e-4f   // log(1/1e-4 - 1) * 1e-4 -> f32
#define EPS_F   1e-10f
#define ZFAR_F  100.0f
#define ZNEAR_F 1.0f
#define RM      0.0304f                 // > sqrt(BLUR_F) = 0.0303484

#define SENT 0xFFFFFFFFFFFFFFFFull

__device__ __forceinline__ float frcp(float x) { return __builtin_amdgcn_rcpf(x); }

__device__ __forceinline__ float edge_d2(float px, float py,
                                         float ax, float ay,
                                         float bx, float by) {
    float abx = bx - ax, aby = by - ay;
    float apx = px - ax, apy = py - ay;
    float t = (apx*abx + apy*aby) * frcp(abx*abx + aby*aby + 1e-12f);
    t = fminf(fmaxf(t, 0.0f), 1.0f);
    float dx = apx - t*abx, dy = apy - t*aby;
    return dx*dx + dy*dy;
}

struct Rast { float b0, b1, b2, zpix, dists; };

__device__ __forceinline__ Rast rasterize_s(float px, float py,
                                            float v0x, float v0y, float v1x, float v1y,
                                            float v2x, float v2y,
                                            float z0, float z1, float z2) {
    Rast r;
    float e1x=v1x-v0x, e1y=v1y-v0y, e2x=v2x-v0x, e2y=v2y-v0y;
    float dx=px-v0x, dy=py-v0y;
    float rden = frcp(e1x*e2y - e1y*e2x + 1e-12f);
    r.b1 = (dx*e2y - dy*e2x) * rden;
    r.b2 = (e1x*dy - e1y*dx) * rden;
    r.b0 = 1.0f - r.b1 - r.b2;
    r.zpix = r.b0*z0 + r.b1*z1 + r.b2*z2;
    bool inside = (r.b0 >= 0.0f) && (r.b1 >= 0.0f) && (r.b2 >= 0.0f);
    float d2 = edge_d2(px, py, v0x, v0y, v1x, v1y);
    d2 = fminf(d2, edge_d2(px, py, v1x, v1y, v2x, v2y));
    d2 = fminf(d2, edge_d2(px, py, v2x, v2y, v0x, v0y));
    r.dists = inside ? -d2 : d2;
    return r;
}

__device__ __forceinline__ unsigned long long packzf(float z, int f) {
    return (((unsigned long long)__float_as_uint(z)) << 32) | (unsigned int)f;
}

__device__ __forceinline__ unsigned long long shflx64(unsigned long long v, int m) {
    int lo = __shfl_xor((int)(unsigned)(v & 0xffffffffull), m, 64);
    int hi = __shfl_xor((int)(unsigned)(v >> 32), m, 64);
    return ((unsigned long long)(unsigned)hi << 32) | (unsigned)lo;
}

// ============ single fused kernel: transform + bin + render, all in LDS ============
__global__ __launch_bounds__(512) void render_fused_kernel(
    const float* __restrict__ mpos,    // (B,M,3)
    const float* __restrict__ mrot,    // (B,M,3,3)
    const float* __restrict__ mscale,  // (B,M,3)
    const float* __restrict__ cpos,    // (B,3)
    const float* __restrict__ crot,    // (B,3,3)
    const float* __restrict__ verts,   // (M,V,3)
    const int*   __restrict__ faces,   // (M,Fm,3)
    const float* __restrict__ vcol,    // (M,V,3)
    float*       __restrict__ out)     // (B,H,W,4)
{
    const int blocksPerB = NTILE * BPT;
    const int b    = blockIdx.x / blocksPerB;
    const int rem  = blockIdx.x % blocksPerB;
    const int tile = rem / BPT, q = rem % BPT;
    const int wv   = threadIdx.x >> 6;              // 0..7 (one pixel per wave)
    const int lane = threadIdx.x & 63;
    const int t    = threadIdx.x;

    __shared__ float svx[NV], svy[NV], svz[NV];            // 6 KB
    __shared__ float scr_[NV], scg_[NV], scb_[NV];         // 6 KB
    __shared__ float sbx0[NF], sby0[NF], sbx1[NF], sby1[NF]; // 8 KB
    __shared__ int   si0[NF], si1[NF], si2[NF];            // 6 KB
    __shared__ unsigned short slist[NF];                   // 1 KB

    // camera for this batch
    float cr[9];
    #pragma unroll
    for (int i = 0; i < 9; ++i) cr[i] = crot[b*9 + i];
    const float cpx = cpos[b*3+0], cpy = cpos[b*3+1], cpz = cpos[b*3+2];

    // ---- phase 1: transform vertex t + colors -> LDS ----
    {
        int g = t;                         // 0..511
        int m = g >> 8;
        int sb = (b*MM + m)*3, rb = (b*MM + m)*9;
        float v0 = verts[g*3+0] * mscale[sb+0];
        float v1 = verts[g*3+1] * mscale[sb+1];
        float v2 = verts[g*3+2] * mscale[sb+2];
        float wx = mrot[rb+0]*v0 + mrot[rb+1]*v1 + mrot[rb+2]*v2 + mpos[sb+0];
        float wy = mrot[rb+3]*v0 + mrot[rb+4]*v1 + mrot[rb+5]*v2 + mpos[sb+1];
        float wz = mrot[rb+6]*v0 + mrot[rb+7]*v1 + mrot[rb+8]*v2 + mpos[sb+2];
        float cx = wx*cr[0] + wy*cr[3] + wz*cr[6] + cpx;
        float cy = wx*cr[1] + wy*cr[4] + wz*cr[7] + cpy;
        float cz = wx*cr[2] + wy*cr[5] + wz*cr[8] + cpz;
        svx[g] = cx / cz;  svy[g] = cy / cz;  svz[g] = cz;
        scr_[g] = vcol[g*3+0];
        scg_[g] = vcol[g*3+1];
        scb_[g] = vcol[g*3+2];
    }
    __syncthreads();

    // ---- phase 2: face gather + screen bbox -> LDS ----
    {
        int f = t;                         // 0..511
        int off = (f >> 8) << 8;
        int i0 = faces[f*3+0] + off;
        int i1 = faces[f*3+1] + off;
        int i2 = faces[f*3+2] + off;
        si0[f] = i0; si1[f] = i1; si2[f] = i2;
        float x0 = svx[i0], y0 = svy[i0];
        float x1 = svx[i1], y1 = svy[i1];
        float x2 = svx[i2], y2 = svy[i2];
        sbx0[f] = fminf(fminf(x0,x1),x2);
        sby0[f] = fminf(fminf(y0,y1),y2);
        sbx1[f] = fmaxf(fmaxf(x0,x1),x2);
        sby1[f] = fmaxf(fmaxf(y0,y1),y2);
    }
    __syncthreads();

    // ---- phase 3: per-wave redundant binning (ascending face order) ----
    const int ty = tile / TDIM, tx = tile % TDIM;
    const float x_lo = -1.0f + tx * (2.0f / TDIM);
    const float x_hi = x_lo + 2.0f / TDIM;
    const float y_hi = 1.0f - ty * (2.0f / TDIM);
    const float y_lo = y_hi - 2.0f / TDIM;

    int L = 0;
    #pragma unroll
    for (int k = 0; k < 8; ++k) {
        int f = (k << 6) | lane;
        bool hit = (sbx0[f] - RM <= x_hi) && (sbx1[f] + RM >= x_lo) &&
                   (sby0[f] - RM <= y_hi) && (sby1[f] + RM >= y_lo);
        unsigned long long m = __ballot(hit);
        if (hit) {
            int rank = __popcll(m & ((1ull << lane) - 1ull));
            slist[L + rank] = (unsigned short)f;   // every wave writes identical values
        }
        L += __popcll(m);
    }
    // no sync: each wave wrote the complete list itself (same-value races benign)

    // ---- pixel for this wave ----
    const int pi = ty * TSZ + q, pj = tx * TSZ + wv;
    const float px = ((float)pj + 0.5f) * (2.0f / WW) - 1.0f;
    const float py = 1.0f - ((float)pi + 0.5f) * (2.0f / HH);

    // ---- phase 4: scan chunks from LDS ----
    unsigned long long pk[MAXC];
    int validm = 0;
    #pragma unroll
    for (int c = 0; c < MAXC; ++c) {
        pk[c] = SENT;
        if (c * 64 < L) {                            // wave-uniform
            int idx = c * 64 + lane;
            int fc = (idx < L) ? (int)slist[idx] : -1;
            unsigned long long tt = SENT;
            if (fc >= 0) {
                int i0 = si0[fc], i1 = si1[fc], i2 = si2[fc];
                Rast r = rasterize_s(px, py, svx[i0], svy[i0], svx[i1], svy[i1],
                                     svx[i2], svy[i2], svz[i0], svz[i1], svz[i2]);
                if (r.zpix > 0.01f && r.dists <= BLUR_F) tt = packzf(r.zpix, fc);
            }
            pk[c] = tt;
            validm |= (tt != SENT ? 1 : 0) << c;
        }
    }

    const int c0 = __popc(validm);
    int cnt = c0;
    #pragma unroll
    for (int m = 1; m < 64; m <<= 1) cnt += __shfl_xor(cnt, m, 64);

    float nr = 0.0f, ng = 0.0f, nb = 0.0f, dn = 0.0f, ap = 1.0f;
    float zmaxv = EPS_F;

#define AGG(ff, zz) do { \
        int f_ = (ff); float z_ = (zz); \
        int i0_ = si0[f_], i1_ = si1[f_], i2_ = si2[f_]; \
        Rast r_ = rasterize_s(px, py, svx[i0_], svy[i0_], svx[i1_], svy[i1_], \
                              svx[i2_], svy[i2_], svz[i0_], svz[i1_], svz[i2_]); \
        float prob_ = frcp(1.0f + __expf(r_.dists / SIGMA_F)); \
        float zinv_ = (ZFAR_F - z_) / (ZFAR_F - ZNEAR_F); \
        float w_ = prob_ * __expf((zinv_ - zmaxv) / GAMMA_F); \
        nr += w_ * (r_.b0*scr_[i0_] + r_.b1*scr_[i1_] + r_.b2*scr_[i2_]); \
        ng += w_ * (r_.b0*scg_[i0_] + r_.b1*scg_[i1_] + r_.b2*scg_[i2_]); \
        nb += w_ * (r_.b0*scb_[i0_] + r_.b1*scb_[i1_] + r_.b2*scb_[i2_]); \
        dn += w_; \
        ap *= (1.0f - prob_); \
    } while (0)

    if (cnt <= KK) {
        // ---- common path: all candidates included; zmax from butterfly min ----
        unsigned long long lmin = pk[0];
        #pragma unroll
        for (int c = 1; c < MAXC; ++c) lmin = (pk[c] < lmin) ? pk[c] : lmin;
        #pragma unroll
        for (int m = 1; m < 64; m <<= 1) {
            unsigned long long o2 = shflx64(lmin, m);
            lmin = (o2 < lmin) ? o2 : lmin;
        }
        if (cnt > 0) {
            float zming = __uint_as_float((unsigned)(lmin >> 32));
            zmaxv = fmaxf((ZFAR_F - zming) / (ZFAR_F - ZNEAR_F), EPS_F);
        }
        #pragma unroll
        for (int c = 0; c < MAXC; ++c)
            if (validm & (1 << c)) {
                int f = (int)(pk[c] & 0xffffffffull);
                float z = __uint_as_float((unsigned)(pk[c] >> 32));
                AGG(f, z);
            }
    } else if (L <= 64) {
        // ---- single-chunk sort path: bitonic ascending on registers ----
        unsigned long long v = pk[0];
        #pragma unroll
        for (int kk = 2; kk <= 64; kk <<= 1) {
            #pragma unroll
            for (int jj = kk >> 1; jj > 0; jj >>= 1) {
                unsigned long long o2 = shflx64(v, jj);
                bool kmin = ((lane & kk) == 0) == ((lane & jj) == 0);
                v = (kmin == (o2 < v)) ? o2 : v;
            }
        }
        unsigned z0b = (unsigned)__shfl((int)(unsigned)(v >> 32), 0, 64);
        zmaxv = fmaxf((ZFAR_F - __uint_as_float(z0b)) / (ZFAR_F - ZNEAR_F), EPS_F);
        if (lane < KK) {                             // cnt > 16 => all 16 valid
            int f = (int)(v & 0xffffffffull);
            float z = __uint_as_float((unsigned)(v >> 32));
            AGG(f, z);
        }
    } else {
        // ---- multi-chunk & cnt>16 -> pop-min 16 rounds ----
        int remm = validm, inclm = 0;
        float zming = 0.0f;
        for (int r = 0; r < KK; ++r) {
            unsigned long long lm = SENT;
            #pragma unroll
            for (int k = 0; k < MAXC; ++k)
                if (remm & (1 << k)) lm = (pk[k] < lm) ? pk[k] : lm;
            #pragma unroll
            for (int m = 1; m < 64; m <<= 1) {
                unsigned long long o2 = shflx64(lm, m);
                lm = (o2 < lm) ? o2 : lm;
            }
            if (r == 0) zming = __uint_as_float((unsigned)(lm >> 32));
            #pragma unroll
            for (int k = 0; k < MAXC; ++k)
                if ((remm & (1 << k)) && pk[k] == lm) { inclm |= 1 << k; remm &= ~(1 << k); }
        }
        zmaxv = fmaxf((ZFAR_F - zming) / (ZFAR_F - ZNEAR_F), EPS_F);
        #pragma unroll
        for (int k = 0; k < MAXC; ++k)
            if (inclm & (1 << k)) {
                int f = (int)(pk[k] & 0xffffffffull);
                float z = __uint_as_float((unsigned)(pk[k] >> 32));
                AGG(f, z);
            }
    }
#undef AGG

    // ---- wave butterfly reductions (deterministic fixed order) ----
    #pragma unroll
    for (int m = 1; m < 64; m <<= 1) {
        nr += __shfl_xor(nr, m, 64);
        ng += __shfl_xor(ng, m, 64);
        nb += __shfl_xor(nb, m, 64);
        dn += __shfl_xor(dn, m, 64);
        ap *= __shfl_xor(ap, m, 64);
    }
    if (lane == 0) {
        float delta = __expf((EPS_F - zmaxv) / GAMMA_F);
        float dd = dn + delta;
        float4 o4;
        o4.x = (nr + delta) / dd;
        o4.y = (ng + delta) / dd;
        o4.z = (nb + delta) / dd;
        o4.w = 1.0f - ap;
        *reinterpret_cast<float4*>(&out[((size_t)b * NPIX + pi * WW + pj) * 4]) = o4;
    }
}

extern "C" void kernel_launch(void* const* d_in, const int* in_sizes, int n_in,
                              void* d_out, int out_size, void* d_ws, size_t ws_size,
                              hipStream_t stream) {
    const float* mpos   = (const float*)d_in[0];
    const float* mrot   = (const float*)d_in[1];
    const float* mscale = (const float*)d_in[2];
    const float* cpos   = (const float*)d_in[3];
    const float* crot   = (const float*)d_in[4];
    const float* verts  = (const float*)d_in[5];
    const int*   faces  = (const int*)d_in[6];
    const float* vcol   = (const float*)d_in[7];
    float*       out    = (float*)d_out;

    const int B = in_sizes[3] / 3;                  // cam_pos is (B,3)
    dim3 grid(B * NTILE * BPT), block(512);
    render_fused_kernel<<<grid, block, 0, stream>>>(
        mpos, mrot, mscale, cpos, crot, verts, faces, vcol, out);
}

// Round 12
// 39.106 us; speedup vs baseline: 1.3819x; 1.1545x over previous
//
#include <hip/hip_runtime.h>

#pragma clang fp contract(off)

#define HH 96
#define WW 96
#define KK 16
#define MM 2
#define NF 512            // M * Fm
#define NV 512            // M * V
#define NPIX (HH*WW)      // 9216
#define TDIM 12           // tiles per side
#define TSZ 8             // pixels per tile side
#define NTILE (TDIM*TDIM) // 144
#define MAXC 8            // max list chunks (NF/64)
#define BPT 8             // blocks per tile (8 px each)

#define SIGMA_F 1e-4f
#define GAMMA_F 1e-4f
#define BLUR_F  9.210240366975851e-4f   // log(1/1e-4 - 1) * 1e-4 -> f32
#define EPS_F   1e-10f
#define ZFAR_F  100.0f
#define ZNEAR_F 1.0f
#define RM      0.0304f                 // > sqrt(BLUR_F) = 0.0303484

#define SENT 0xFFFFFFFFFFFFFFFFull

__device__ __forceinline__ float frcp(float x) { return __builtin_amdgcn_rcpf(x); }

__device__ __forceinline__ float edge_d2(float px, float py,
                                         float ax, float ay,
                                         float bx, float by) {
    float abx = bx - ax, aby = by - ay;
    float apx = px - ax, apy = py - ay;
    float t = (apx*abx + apy*aby) * frcp(abx*abx + aby*aby + 1e-12f);
    t = fminf(fmaxf(t, 0.0f), 1.0f);
    float dx = apx - t*abx, dy = apy - t*aby;
    return dx*dx + dy*dy;
}

struct Rast { float b0, b1, b2, zpix, dists; };

__device__ __forceinline__ Rast rasterize_s(float px, float py,
                                            float v0x, float v0y, float v1x, float v1y,
                                            float v2x, float v2y,
                                            float z0, float z1, float z2) {
    Rast r;
    float e1x=v1x-v0x, e1y=v1y-v0y, e2x=v2x-v0x, e2y=v2y-v0y;
    float dx=px-v0x, dy=py-v0y;
    float rden = frcp(e1x*e2y - e1y*e2x + 1e-12f);
    r.b1 = (dx*e2y - dy*e2x) * rden;
    r.b2 = (e1x*dy - e1y*dx) * rden;
    r.b0 = 1.0f - r.b1 - r.b2;
    r.zpix = r.b0*z0 + r.b1*z1 + r.b2*z2;
    bool inside = (r.b0 >= 0.0f) && (r.b1 >= 0.0f) && (r.b2 >= 0.0f);
    float d2 = edge_d2(px, py, v0x, v0y, v1x, v1y);
    d2 = fminf(d2, edge_d2(px, py, v1x, v1y, v2x, v2y));
    d2 = fminf(d2, edge_d2(px, py, v2x, v2y, v0x, v0y));
    r.dists = inside ? -d2 : d2;
    return r;
}

__device__ __forceinline__ unsigned long long packzf(float z, int id) {
    return (((unsigned long long)__float_as_uint(z)) << 32) | (unsigned int)id;
}

__device__ __forceinline__ unsigned long long shflx64(unsigned long long v, int m) {
    int lo = __shfl_xor((int)(unsigned)(v & 0xffffffffull), m, 64);
    int hi = __shfl_xor((int)(unsigned)(v >> 32), m, 64);
    return ((unsigned long long)(unsigned)hi << 32) | (unsigned)lo;
}

// center-first concentric-ring tile ordering (heavy central tiles dispatch first)
__device__ __forceinline__ int ring_tile(int ord) {
    int r = ((int)__builtin_sqrtf((float)ord)) >> 1;
    while ((2*r+2)*(2*r+2) <= ord) ++r;
    while (r > 0 && (2*r)*(2*r) > ord) --r;
    int p = ord - 4*r*r;
    int side = 2*r + 2;
    int lo = TDIM/2 - 1 - r;       // 5 - r
    int hi = TDIM/2 + r;           // 6 + r
    int tx, ty;
    if (p < side)              { ty = lo; tx = lo + p; }
    else if (p < 2*side - 1)   { tx = hi; ty = lo + (p - side + 1); }
    else if (p < 3*side - 2)   { ty = hi; tx = hi - (p - (2*side - 1) + 1); }
    else                       { tx = lo; ty = hi - (p - (3*side - 2) + 1); }
    return ty * TDIM + tx;
}

// ============ single fused kernel: transform + bin + render, all in LDS ============
__global__ __launch_bounds__(512) void render_fused_kernel(
    const float* __restrict__ mpos,    // (B,M,3)
    const float* __restrict__ mrot,    // (B,M,3,3)
    const float* __restrict__ mscale,  // (B,M,3)
    const float* __restrict__ cpos,    // (B,3)
    const float* __restrict__ crot,    // (B,3,3)
    const float* __restrict__ verts,   // (M,V,3)
    const int*   __restrict__ faces,   // (M,Fm,3)
    const float* __restrict__ vcol,    // (M,V,3)
    float*       __restrict__ out)     // (B,H,W,4)
{
    const int blocksPerB = NTILE * BPT;
    const int b    = blockIdx.x / blocksPerB;
    const int rem  = blockIdx.x % blocksPerB;
    const int tile = ring_tile(rem / BPT);
    const int q    = rem % BPT;
    const int wv   = threadIdx.x >> 6;              // 0..7 (one pixel per wave)
    const int lane = threadIdx.x & 63;
    const int t    = threadIdx.x;

    __shared__ float2 svxy[NV];                            // 4 KB
    __shared__ float  svz[NV];                             // 2 KB
    __shared__ float4 scol[NV];                            // 8 KB
    __shared__ float  sbx0[NF], sby0[NF], sbx1[NF], sby1[NF]; // 8 KB
    __shared__ int    si0[NF], si1[NF], si2[NF];           // 6 KB
    __shared__ int    cl0[NF], cl1[NF], cl2[NF];           // 6 KB

    // camera for this batch
    float cr[9];
    #pragma unroll
    for (int i = 0; i < 9; ++i) cr[i] = crot[b*9 + i];
    const float cpx = cpos[b*3+0], cpy = cpos[b*3+1], cpz = cpos[b*3+2];

    // ---- phase 1: transform vertex t + colors -> LDS ----
    {
        int g = t;                         // 0..511
        int m = g >> 8;
        int sb = (b*MM + m)*3, rb = (b*MM + m)*9;
        float v0 = verts[g*3+0] * mscale[sb+0];
        float v1 = verts[g*3+1] * mscale[sb+1];
        float v2 = verts[g*3+2] * mscale[sb+2];
        float wx = mrot[rb+0]*v0 + mrot[rb+1]*v1 + mrot[rb+2]*v2 + mpos[sb+0];
        float wy = mrot[rb+3]*v0 + mrot[rb+4]*v1 + mrot[rb+5]*v2 + mpos[sb+1];
        float wz = mrot[rb+6]*v0 + mrot[rb+7]*v1 + mrot[rb+8]*v2 + mpos[sb+2];
        float cx = wx*cr[0] + wy*cr[3] + wz*cr[6] + cpx;
        float cy = wx*cr[1] + wy*cr[4] + wz*cr[7] + cpy;
        float cz = wx*cr[2] + wy*cr[5] + wz*cr[8] + cpz;
        svxy[g] = make_float2(cx / cz, cy / cz);
        svz[g]  = cz;
        scol[g] = make_float4(vcol[g*3+0], vcol[g*3+1], vcol[g*3+2], 0.0f);
    }
    __syncthreads();

    // ---- phase 2: face gather + screen bbox -> LDS ----
    {
        int f = t;                         // 0..511
        int off = (f >> 8) << 8;
        int i0 = faces[f*3+0] + off;
        int i1 = faces[f*3+1] + off;
        int i2 = faces[f*3+2] + off;
        si0[f] = i0; si1[f] = i1; si2[f] = i2;
        float2 p0 = svxy[i0], p1 = svxy[i1], p2 = svxy[i2];
        sbx0[f] = fminf(fminf(p0.x,p1.x),p2.x);
        sby0[f] = fminf(fminf(p0.y,p1.y),p2.y);
        sbx1[f] = fmaxf(fmaxf(p0.x,p1.x),p2.x);
        sby1[f] = fmaxf(fmaxf(p0.y,p1.y),p2.y);
    }
    __syncthreads();

    // ---- phase 3: per-wave binning; preload bbox for ILP, then ballot rounds ----
    const int ty = tile / TDIM, tx = tile % TDIM;
    const float x_lo = -1.0f + tx * (2.0f / TDIM);
    const float x_hi = x_lo + 2.0f / TDIM;
    const float y_hi = 1.0f - ty * (2.0f / TDIM);
    const float y_lo = y_hi - 2.0f / TDIM;

    float bx0[8], by0[8], bx1[8], by1[8];
    #pragma unroll
    for (int k = 0; k < 8; ++k) {
        int f = (k << 6) | lane;
        bx0[k] = sbx0[f]; by0[k] = sby0[f];
        bx1[k] = sbx1[f]; by1[k] = sby1[f];
    }
    int hitm = 0;
    #pragma unroll
    for (int k = 0; k < 8; ++k) {
        bool hit = (bx0[k] - RM <= x_hi) && (bx1[k] + RM >= x_lo) &&
                   (by0[k] - RM <= y_hi) && (by1[k] + RM >= y_lo);
        hitm |= (hit ? 1 : 0) << k;
    }
    int L = 0;
    #pragma unroll
    for (int k = 0; k < 8; ++k) {
        bool hit = (hitm >> k) & 1;
        unsigned long long m = __ballot(hit);
        if (hit) {
            int f = (k << 6) | lane;
            int pos = L + __popcll(m & ((1ull << lane) - 1ull));
            cl0[pos] = si0[f];             // every wave writes identical values
            cl1[pos] = si1[f];
            cl2[pos] = si2[f];
        }
        L += __popcll(m);
    }
    // no sync: each wave wrote the complete compacted list itself

    // ---- pixel for this wave ----
    const int pi = ty * TSZ + q, pj = tx * TSZ + wv;
    const float px = ((float)pj + 0.5f) * (2.0f / WW) - 1.0f;
    const float py = 1.0f - ((float)pi + 0.5f) * (2.0f / HH);

    // ---- phase 4: scan compacted list (stride-1 cl reads -> sv gathers) ----
    unsigned long long pk[MAXC];
    int validm = 0;
    #pragma unroll
    for (int c = 0; c < MAXC; ++c) {
        pk[c] = SENT;
        if (c * 64 < L) {                            // wave-uniform
            int idx = c * 64 + lane;
            unsigned long long tt = SENT;
            if (idx < L) {
                int i0 = cl0[idx], i1 = cl1[idx], i2 = cl2[idx];
                float2 p0 = svxy[i0], p1 = svxy[i1], p2 = svxy[i2];
                float z0 = svz[i0], z1 = svz[i1], z2 = svz[i2];
                Rast r = rasterize_s(px, py, p0.x, p0.y, p1.x, p1.y,
                                     p2.x, p2.y, z0, z1, z2);
                if (r.zpix > 0.01f && r.dists <= BLUR_F) tt = packzf(r.zpix, idx);
            }
            pk[c] = tt;
            validm |= (tt != SENT ? 1 : 0) << c;
        }
    }

    const int c0 = __popc(validm);
    int cnt = c0;
    #pragma unroll
    for (int m = 1; m < 64; m <<= 1) cnt += __shfl_xor(cnt, m, 64);

    float nr = 0.0f, ng = 0.0f, nb = 0.0f, dn = 0.0f, ap = 1.0f;
    float zmaxv = EPS_F;

#define AGG(pp, zz) do { \
        int p_ = (pp); float z_ = (zz); \
        int i0_ = cl0[p_], i1_ = cl1[p_], i2_ = cl2[p_]; \
        float2 q0_ = svxy[i0_], q1_ = svxy[i1_], q2_ = svxy[i2_]; \
        float z0_ = svz[i0_], z1_ = svz[i1_], z2_ = svz[i2_]; \
        Rast r_ = rasterize_s(px, py, q0_.x, q0_.y, q1_.x, q1_.y, \
                              q2_.x, q2_.y, z0_, z1_, z2_); \
        float prob_ = frcp(1.0f + __expf(r_.dists / SIGMA_F)); \
        float zinv_ = (ZFAR_F - z_) / (ZFAR_F - ZNEAR_F); \
        float w_ = prob_ * __expf((zinv_ - zmaxv) / GAMMA_F); \
        float4 c0_ = scol[i0_], c1_ = scol[i1_], c2_ = scol[i2_]; \
        nr += w_ * (r_.b0*c0_.x + r_.b1*c1_.x + r_.b2*c2_.x); \
        ng += w_ * (r_.b0*c0_.y + r_.b1*c1_.y + r_.b2*c2_.y); \
        nb += w_ * (r_.b0*c0_.z + r_.b1*c1_.z + r_.b2*c2_.z); \
        dn += w_; \
        ap *= (1.0f - prob_); \
    } while (0)

    if (cnt <= KK) {
        // ---- common path: all candidates included; zmax from butterfly min ----
        unsigned long long lmin = pk[0];
        #pragma unroll
        for (int c = 1; c < MAXC; ++c) lmin = (pk[c] < lmin) ? pk[c] : lmin;
        #pragma unroll
        for (int m = 1; m < 64; m <<= 1) {
            unsigned long long o2 = shflx64(lmin, m);
            lmin = (o2 < lmin) ? o2 : lmin;
        }
        if (cnt > 0) {
            float zming = __uint_as_float((unsigned)(lmin >> 32));
            zmaxv = fmaxf((ZFAR_F - zming) / (ZFAR_F - ZNEAR_F), EPS_F);
        }
        #pragma unroll
        for (int c = 0; c < MAXC; ++c)
            if (validm & (1 << c)) {
                int id = (int)(pk[c] & 0xffffffffull);
                float z = __uint_as_float((unsigned)(pk[c] >> 32));
                AGG(id, z);
            }
    } else if (L <= 64) {
        // ---- single-chunk sort path: bitonic ascending on registers ----
        unsigned long long v = pk[0];
        #pragma unroll
        for (int kk = 2; kk <= 64; kk <<= 1) {
            #pragma unroll
            for (int jj = kk >> 1; jj > 0; jj >>= 1) {
                unsigned long long o2 = shflx64(v, jj);
                bool kmin = ((lane & kk) == 0) == ((lane & jj) == 0);
                v = (kmin == (o2 < v)) ? o2 : v;
            }
        }
        unsigned z0b = (unsigned)__shfl((int)(unsigned)(v >> 32), 0, 64);
        zmaxv = fmaxf((ZFAR_F - __uint_as_float(z0b)) / (ZFAR_F - ZNEAR_F), EPS_F);
        if (lane < KK) {                             // cnt > 16 => all 16 valid
            int id = (int)(v & 0xffffffffull);
            float z = __uint_as_float((unsigned)(v >> 32));
            AGG(id, z);
        }
    } else {
        // ---- multi-chunk & cnt>16 -> pop-min 16 rounds ----
        int remm = validm, inclm = 0;
        float zming = 0.0f;
        for (int r = 0; r < KK; ++r) {
            unsigned long long lm = SENT;
            #pragma unroll
            for (int k = 0; k < MAXC; ++k)
                if (remm & (1 << k)) lm = (pk[k] < lm) ? pk[k] : lm;
            #pragma unroll
            for (int m = 1; m < 64; m <<= 1) {
                unsigned long long o2 = shflx64(lm, m);
                lm = (o2 < lm) ? o2 : lm;
            }
            if (r == 0) zming = __uint_as_float((unsigned)(lm >> 32));
            #pragma unroll
            for (int k = 0; k < MAXC; ++k)
                if ((remm & (1 << k)) && pk[k] == lm) { inclm |= 1 << k; remm &= ~(1 << k); }
        }
        zmaxv = fmaxf((ZFAR_F - zming) / (ZFAR_F - ZNEAR_F), EPS_F);
        #pragma unroll
        for (int k = 0; k < MAXC; ++k)
            if (inclm & (1 << k)) {
                int id = (int)(pk[k] & 0xffffffffull);
                float z = __uint_as_float((unsigned)(pk[k] >> 32));
                AGG(id, z);
            }
    }
#undef AGG

    // ---- wave butterfly reductions (deterministic fixed order) ----
    #pragma unroll
    for (int m = 1; m < 64; m <<= 1) {
        nr += __shfl_xor(nr, m, 64);
        ng += __shfl_xor(ng, m, 64);
        nb += __shfl_xor(nb, m, 64);
        dn += __shfl_xor(dn, m, 64);
        ap *= __shfl_xor(ap, m, 64);
    }
    if (lane == 0) {
        float delta = __expf((EPS_F - zmaxv) / GAMMA_F);
        float dd = dn + delta;
        float4 o4;
        o4.x = (nr + delta) / dd;
        o4.y = (ng + delta) / dd;
        o4.z = (nb + delta) / dd;
        o4.w = 1.0f - ap;
        *reinterpret_cast<float4*>(&out[((size_t)b * NPIX + pi * WW + pj) * 4]) = o4;
    }
}

extern "C" void kernel_launch(void* const* d_in, const int* in_sizes, int n_in,
                              void* d_out, int out_size, void* d_ws, size_t ws_size,
                              hipStream_t stream) {
    const float* mpos   = (const float*)d_in[0];
    const float* mrot   = (const float*)d_in[1];
    const float* mscale = (const float*)d_in[2];
    const float* cpos   = (const float*)d_in[3];
    const float* crot   = (const float*)d_in[4];
    const float* verts  = (const float*)d_in[5];
    const int*   faces  = (const int*)d_in[6];
    const float* vcol   = (const float*)d_in[7];
    float*       out    = (float*)d_out;

    const int B = in_sizes[3] / 3;                  // cam_pos is (B,3)
    dim3 grid(B * NTILE * BPT), block(512);
    render_fused_kernel<<<grid, block, 0, stream>>>(
        mpos, mrot, mscale, cpos, crot, verts, faces, vcol, out);
}